// Round 10
// baseline (24064.360 us; speedup 1.0000x reference)
//
#include <hip/hip_runtime.h>
#include <hip/hip_bf16.h>
#include <math.h>

#define B_  2048
#define S_  128
#define H_  512
#define NSTEP 63
#define NBLK 128
#define R_   16      // rows per block
#define THREADS 1024 // 16 waves
#define FP_ 129      // f32 LDS stride (bank-spread)

typedef __bf16 bf16x8 __attribute__((ext_vector_type(8)));
typedef float  f32x4  __attribute__((ext_vector_type(4)));
typedef unsigned short u16x8 __attribute__((ext_vector_type(8)));

static __device__ __forceinline__ void f2b2(float v, unsigned short& hi, unsigned short& lo)
{
    __hip_bfloat16 h = __float2bfloat16(v);
    float r = v - __bfloat162float(h);
    __hip_bfloat16 l = __float2bfloat16(r);
    hi = __builtin_bit_cast(unsigned short, h);
    lo = __builtin_bit_cast(unsigned short, l);
}

static __device__ __forceinline__ bf16x8 frag_ld(const unsigned short* p)
{
    return __builtin_bit_cast(bf16x8, *(const u16x8*)p);
}

// Per-wave GEMM, software-pipelined (distance-1 register double-buffer on the
// global-streamed B operand; named buffers keep indexing static -> no scratch).
// A (16 x Kd) from LDS [row][k]; B from global W^T [n][Kb] hi/lo planes.
// 3-MFMA split: ah*bh + ah*bl + al*bh, f32 accum.
// A-frag: row = lane&15, k = (lane>>4)*8 ; B-frag: n-row = nBase+j*16+(lane&15).
template<int G>
static __device__ __forceinline__ void wgemm(
    const unsigned short* __restrict__ Ah, const unsigned short* __restrict__ Al, int lda, int Kd,
    const unsigned short* __restrict__ Bh, const unsigned short* __restrict__ Bl, int Kb,
    int nBase, int lane, f32x4 (&acc)[G])
{
    const int r16 = lane & 15, kg = lane >> 4;
    const unsigned short* ah = Ah + r16*lda + kg*8;
    const unsigned short* al = Al + r16*lda + kg*8;
    const unsigned short* bh0 = Bh + (size_t)(nBase + r16)*Kb + kg*8;
    const unsigned short* bl0 = Bl + (size_t)(nBase + r16)*Kb + kg*8;

    bf16x8 cbh[G], cbl[G], pbh[G], pbl[G];
#pragma unroll
    for (int j = 0; j < G; ++j) {
        cbh[j] = frag_ld(bh0 + (size_t)j*16*Kb);
        cbl[j] = frag_ld(bl0 + (size_t)j*16*Kb);
    }
    for (int k = 0; k < Kd; k += 64) {
        // prefetch k+32 while current MFMAs run
#pragma unroll
        for (int j = 0; j < G; ++j) {
            pbh[j] = frag_ld(bh0 + (size_t)j*16*Kb + k + 32);
            pbl[j] = frag_ld(bl0 + (size_t)j*16*Kb + k + 32);
        }
        {
            bf16x8 a_h = frag_ld(ah + k), a_l = frag_ld(al + k);
#pragma unroll
            for (int j = 0; j < G; ++j) {
                acc[j] = __builtin_amdgcn_mfma_f32_16x16x32_bf16(a_h, cbh[j], acc[j], 0, 0, 0);
                acc[j] = __builtin_amdgcn_mfma_f32_16x16x32_bf16(a_h, cbl[j], acc[j], 0, 0, 0);
                acc[j] = __builtin_amdgcn_mfma_f32_16x16x32_bf16(a_l, cbh[j], acc[j], 0, 0, 0);
            }
        }
        if (k + 64 < Kd) {
            // prefetch k+64 (next iter's "current")
#pragma unroll
            for (int j = 0; j < G; ++j) {
                cbh[j] = frag_ld(bh0 + (size_t)j*16*Kb + k + 64);
                cbl[j] = frag_ld(bl0 + (size_t)j*16*Kb + k + 64);
            }
        }
        {
            bf16x8 a_h = frag_ld(ah + k + 32), a_l = frag_ld(al + k + 32);
#pragma unroll
            for (int j = 0; j < G; ++j) {
                acc[j] = __builtin_amdgcn_mfma_f32_16x16x32_bf16(a_h, pbh[j], acc[j], 0, 0, 0);
                acc[j] = __builtin_amdgcn_mfma_f32_16x16x32_bf16(a_h, pbl[j], acc[j], 0, 0, 0);
                acc[j] = __builtin_amdgcn_mfma_f32_16x16x32_bf16(a_l, pbh[j], acc[j], 0, 0, 0);
            }
        }
    }
}

// Persistent row-slab kernel: block owns 16 batch rows for ALL 63 steps.
// All activations in LDS; weights streamed (read-only, shared via L2).
// No cross-block data flow -> no fences needed.
// amdgpu_waves_per_eu(4,4): pin exactly 4 waves/SIMD (1 block/CU -- LDS-capped anyway)
// so the backend may allocate up to 128 VGPRs instead of spilling at 64 (r9 lesson).
// C/D frag: col = lane&15, row = (lane>>4)*4 + reg.
__global__ __launch_bounds__(THREADS)
__attribute__((amdgpu_waves_per_eu(4, 4)))
void sde_k(
    const float* __restrict__ ts, const float* __restrict__ dW,
    const float* __restrict__ g_w1, const float* __restrict__ g_b1,
    const float* __restrict__ f_w1, const float* __restrict__ f_b1,
    const float* __restrict__ f_b2, const float* __restrict__ f_b3,
    const float* __restrict__ g_b2,
    const unsigned short* __restrict__ w1tH, const unsigned short* __restrict__ w1tL,
    const unsigned short* __restrict__ gw2H, const unsigned short* __restrict__ gw2L,
    const unsigned short* __restrict__ fw2H, const unsigned short* __restrict__ fw2L,
    const unsigned short* __restrict__ fw3H, const unsigned short* __restrict__ fw3L,
    float* __restrict__ out, unsigned int* __restrict__ ctrs)
{
    __shared__ __align__(16) unsigned short HAh[R_*1032], HAl[R_*1032]; // 16x1024 (g|f)
    __shared__ __align__(16) unsigned short HBh[R_*520],  HBl[R_*520];  // 16x512
    __shared__ __align__(16) unsigned short ycH[R_*136],  ycL[R_*136];  // 16x128
    __shared__ __align__(16) unsigned short ytH[R_*136],  ytL[R_*136];
    __shared__ float y_s[R_*FP_], gp_s[R_*FP_], dr_s[R_*FP_];

    const int bid = blockIdx.x, tid = threadIdx.x;
    const int w = tid >> 6, lane = tid & 63;
    const int r16 = lane & 15, kg = lane >> 4;
    const int r0 = bid * R_;

    for (int i = tid; i < R_*128; i += THREADS) {
        int row = i >> 7, col = i & 127;
        float v = out[(size_t)(r0 + row)*S_ + col];
        y_s[row*FP_ + col] = v;
        unsigned short h, lo; f2b2(v, h, lo);
        ycH[row*136 + col] = h; ycL[row*136 + col] = lo;
    }
    __syncthreads();

    for (int step = 0; step < NSTEP; ++step) {
        const float tcur = ts[3+step];
        const float dt   = ts[4+step] - tcur;
        const float sq   = sqrtf(dt);
        const float* dWs = dW + (size_t)step * B_ * 16;
        float dwv[4];
#pragma unroll
        for (int reg = 0; reg < 4; ++reg)
            dwv[reg] = dWs[(r0 + kg*4 + reg)*16 + r16] * sq;

        // ---- P1: HA = relu([t,yc] @ [g_w1|f_w1]) ; N=1024, 4 frags/wave
        {
            f32x4 acc[4] = {};
            wgemm<4>(ycH, ycL, 136, 128, w1tH, w1tL, 128, w*64, lane, acc);
#pragma unroll
            for (int j = 0; j < 4; ++j) {
                int col = w*64 + j*16 + r16;
                float be = (col < 512) ? (g_b1[col] + tcur*g_w1[col])
                                       : (f_b1[col-512] + tcur*f_w1[col-512]);
#pragma unroll
                for (int reg = 0; reg < 4; ++reg) {
                    int row = kg*4 + reg;
                    float v = fmaxf(acc[j][reg] + be, 0.f);
                    unsigned short h, lo; f2b2(v, h, lo);
                    HAh[row*1032 + col] = h; HAl[row*1032 + col] = lo;
                }
            }
        }
        __syncthreads();

        // ---- P2g: gp = contract(HA_g @ g_w2 + b, dW*sq) ; yt = y + gp
        for (int grp = 0; grp < 2; ++grp) {
            f32x4 acc[4] = {};
            int nb = w*128 + grp*64;
            wgemm<4>(HAh, HAl, 1032, 512, gw2H, gw2L, 512, nb, lane, acc);
#pragma unroll
            for (int j = 0; j < 4; ++j) {
                int s = w*8 + grp*4 + j;
                float bb = g_b2[nb + j*16 + r16];
#pragma unroll
                for (int reg = 0; reg < 4; ++reg) {
                    float m = (acc[j][reg] + bb) * dwv[reg];
                    m += __shfl_xor(m,1); m += __shfl_xor(m,2);
                    m += __shfl_xor(m,4); m += __shfl_xor(m,8);
                    if (r16 == 0) {
                        int row = kg*4 + reg;
                        gp_s[row*FP_ + s] = m;
                        float yv = y_s[row*FP_ + s] + m;
                        unsigned short h, lo; f2b2(yv, h, lo);
                        ytH[row*136 + s] = h; ytL[row*136 + s] = lo;
                    }
                }
            }
        }
        // ---- P2f: HB = relu(HA_f @ f_w2 + b)
        {
            f32x4 acc[2] = {};
            wgemm<2>(HAh + 512, HAl + 512, 1032, 512, fw2H, fw2L, 512, w*32, lane, acc);
#pragma unroll
            for (int j = 0; j < 2; ++j) {
                int col = w*32 + j*16 + r16;
                float be = f_b2[col];
#pragma unroll
                for (int reg = 0; reg < 4; ++reg) {
                    int row = kg*4 + reg;
                    float v = fmaxf(acc[j][reg] + be, 0.f);
                    unsigned short h, lo; f2b2(v, h, lo);
                    HBh[row*520 + col] = h; HBl[row*520 + col] = lo;
                }
            }
        }
        __syncthreads();

        // ---- P3a: HA2 = relu([t,yt] @ g_w1 + b) -> overwrite HA cols 0..511
        {
            f32x4 acc[2] = {};
            wgemm<2>(ytH, ytL, 136, 128, w1tH, w1tL, 128, w*32, lane, acc);
#pragma unroll
            for (int j = 0; j < 2; ++j) {
                int col = w*32 + j*16 + r16;           // 0..511
                float be = g_b1[col] + tcur*g_w1[col];
#pragma unroll
                for (int reg = 0; reg < 4; ++reg) {
                    int row = kg*4 + reg;
                    float v = fmaxf(acc[j][reg] + be, 0.f);
                    unsigned short h, lo; f2b2(v, h, lo);
                    HAh[row*1032 + col] = h; HAl[row*1032 + col] = lo;
                }
            }
        }
        // ---- P3b: drift = HB @ f_w3 + b ; waves 0..7
        if (w < 8) {
            f32x4 acc1[1] = {};
            wgemm<1>(HBh, HBl, 520, 512, fw3H, fw3L, 512, w*16, lane, acc1);
            int col = w*16 + r16;
            float be = f_b3[col];
#pragma unroll
            for (int reg = 0; reg < 4; ++reg)
                dr_s[(kg*4 + reg)*FP_ + col] = acc1[0][reg] + be;
        }
        __syncthreads();

        // ---- P4: gp2 + final update -> y1 (global out), y_s, yc
        float* y1 = out + (size_t)(step+1) * B_ * S_;
        for (int grp = 0; grp < 2; ++grp) {
            f32x4 acc[4] = {};
            int nb = w*128 + grp*64;
            wgemm<4>(HAh, HAl, 1032, 512, gw2H, gw2L, 512, nb, lane, acc);
#pragma unroll
            for (int j = 0; j < 4; ++j) {
                int s = w*8 + grp*4 + j;
                float bb = g_b2[nb + j*16 + r16];
#pragma unroll
                for (int reg = 0; reg < 4; ++reg) {
                    float m = (acc[j][reg] + bb) * dwv[reg];
                    m += __shfl_xor(m,1); m += __shfl_xor(m,2);
                    m += __shfl_xor(m,4); m += __shfl_xor(m,8);
                    if (r16 == 0) {
                        int row = kg*4 + reg;
                        int idx = row*FP_ + s;
                        float v1 = y_s[idx] + dr_s[idx]*dt + 0.5f*(gp_s[idx] + m);
                        y1[(size_t)(r0 + row)*S_ + s] = v1;
                        y_s[idx] = v1;
                        unsigned short h, lo; f2b2(v1, h, lo);
                        ycH[row*136 + s] = h; ycL[row*136 + s] = lo;
                    }
                }
            }
        }

        // ---- soft pacing barrier (relaxed RMW only, no fences; perf-only)
        __syncthreads();
        if (tid == 0) {
            __hip_atomic_fetch_add(&ctrs[step], 1u, __ATOMIC_RELAXED, __HIP_MEMORY_SCOPE_AGENT);
            int spins = 0;
            while (__hip_atomic_fetch_add(&ctrs[step], 0u, __ATOMIC_RELAXED, __HIP_MEMORY_SCOPE_AGENT) < NBLK) {
                __builtin_amdgcn_s_sleep(2);
                if (++spins > (1<<20)) break;   // safety valve (pacing only)
            }
        }
        __syncthreads();
    }
}

// transpose + split-cast: in (rows=[rowOff..rowOff+Kd) x N f32) -> out [N][Kd] hi/lo
__global__ __launch_bounds__(256) void tcast_k(
    const float* __restrict__ in, int rowOff, int Kd, int N,
    unsigned short* __restrict__ outH, unsigned short* __restrict__ outL)
{
    __shared__ float tl[32][33];
    const int kb = blockIdx.x*32, nb = blockIdx.y*32;
    const int tx = threadIdx.x, ty = threadIdx.y;
    for (int r = ty; r < 32; r += 8)
        tl[r][tx] = in[(size_t)(rowOff + kb + r)*N + nb + tx];
    __syncthreads();
    for (int r = ty; r < 32; r += 8) {
        unsigned short h, lo; f2b2(tl[tx][r], h, lo);
        size_t o = (size_t)(nb + r)*Kd + kb + tx;
        outH[o] = h; outL[o] = lo;
    }
}

__global__ __launch_bounds__(128) void encoder_k(
    const float* __restrict__ x,
    const float* __restrict__ w1, const float* __restrict__ b1,
    const float* __restrict__ w2, const float* __restrict__ b2,
    float* __restrict__ y0)
{
    int b = blockIdx.x;
    __shared__ float h[H_];
    int tid = threadIdx.x;
    float x0 = x[b*3+0], x1 = x[b*3+1], x2 = x[b*3+2];
    for (int i = tid; i < H_; i += 128)
        h[i] = fmaxf(x0*w1[i] + x1*w1[H_+i] + x2*w1[2*H_+i] + b1[i], 0.f);
    __syncthreads();
    float acc = b2[tid];
    for (int k = 0; k < H_; ++k) acc += h[k]*w2[k*S_+tid];
    y0[(size_t)b*S_ + tid] = acc;
}

__global__ void zero_ctr_k(unsigned int* c) { c[threadIdx.x] = 0; }

extern "C" void kernel_launch(void* const* d_in, const int* in_sizes, int n_in,
                              void* d_out, int out_size, void* d_ws, size_t ws_size,
                              hipStream_t stream)
{
    const float* ts     = (const float*)d_in[0];
    const float* x      = (const float*)d_in[1];
    const float* enc_w1 = (const float*)d_in[2];
    const float* enc_b1 = (const float*)d_in[3];
    const float* enc_w2 = (const float*)d_in[4];
    const float* enc_b2 = (const float*)d_in[5];
    const float* f_w1   = (const float*)d_in[6];
    const float* f_b1   = (const float*)d_in[7];
    const float* f_w2   = (const float*)d_in[8];
    const float* f_b2   = (const float*)d_in[9];
    const float* f_w3   = (const float*)d_in[10];
    const float* f_b3   = (const float*)d_in[11];
    const float* g_w1   = (const float*)d_in[12];
    const float* g_b1   = (const float*)d_in[13];
    const float* g_w2   = (const float*)d_in[14];
    const float* g_b2   = (const float*)d_in[15];
    const float* dW     = (const float*)d_in[16];

    float* out = (float*)d_out;
    unsigned short* wsp = (unsigned short*)d_ws;

    unsigned short* w1tH = wsp;                     // [1024][128]
    unsigned short* w1tL = w1tH + 1024*128;
    unsigned short* gw2H = w1tL + 1024*128;         // [2048][512]
    unsigned short* gw2L = gw2H + 2048*512;
    unsigned short* fw2H = gw2L + 2048*512;         // [512][512]
    unsigned short* fw2L = fw2H + 512*512;
    unsigned short* fw3H = fw2L + 512*512;          // [128][512]
    unsigned short* fw3L = fw3H + 128*512;
    unsigned int*   ctrs = (unsigned int*)(fw3L + 128*512);  // 64 uints

    dim3 tb(32,8);
    tcast_k<<<dim3(4,16),  tb, 0, stream>>>(g_w1, 1, 128, 512,  w1tH,         w1tL);
    tcast_k<<<dim3(4,16),  tb, 0, stream>>>(f_w1, 1, 128, 512,  w1tH+512*128, w1tL+512*128);
    tcast_k<<<dim3(16,16), tb, 0, stream>>>(f_w2, 0, 512, 512,  fw2H,         fw2L);
    tcast_k<<<dim3(16,4),  tb, 0, stream>>>(f_w3, 0, 512, 128,  fw3H,         fw3L);
    tcast_k<<<dim3(16,64), tb, 0, stream>>>(g_w2, 0, 512, 2048, gw2H,         gw2L);

    encoder_k<<<B_, 128, 0, stream>>>(x, enc_w1, enc_b1, enc_w2, enc_b2, out);
    zero_ctr_k<<<1, 64, 0, stream>>>(ctrs);

    sde_k<<<NBLK, THREADS, 0, stream>>>(
        ts, dW, g_w1, g_b1, f_w1, f_b1, f_b2, f_b3, g_b2,
        w1tH, w1tL, gw2H, gw2L, fw2H, fw2L, fw3H, fw3L,
        out, ctrs);
}

// Round 11
// 14659.409 us; speedup vs baseline: 1.6416x; 1.6416x over previous
//
#include <hip/hip_runtime.h>
#include <hip/hip_bf16.h>
#include <math.h>

#define B_  2048
#define S_  128
#define H_  512
#define NSTEP 63
#define NBLK 256      // 128 row-slabs x 2 column-groups
#define R_   16       // rows per slab
#define THREADS 512   // 8 waves
#define AST 1028      // HA stride (shorts): 514 dw == 2 mod 32 -> conflict-free frag reads
#define YST 132       // yc/yt stride: 66 dw == 2 mod 32
#define FP_ 129       // f32 stride

typedef __bf16 bf16x8 __attribute__((ext_vector_type(8)));
typedef float  f32x4  __attribute__((ext_vector_type(4)));
typedef unsigned short u16x8 __attribute__((ext_vector_type(8)));

static __device__ __forceinline__ void f2b2(float v, unsigned short& hi, unsigned short& lo)
{
    __hip_bfloat16 h = __float2bfloat16(v);
    float r = v - __bfloat162float(h);
    __hip_bfloat16 l = __float2bfloat16(r);
    hi = __builtin_bit_cast(unsigned short, h);
    lo = __builtin_bit_cast(unsigned short, l);
}

static __device__ __forceinline__ bf16x8 frag_ld(const unsigned short* p)
{
    return __builtin_bit_cast(bf16x8, *(const u16x8*)p);
}

// cross-block exchange via atomic RMW/exchange: executes at the device coherence
// point -> no fences, no cache invalidation needed (r5-r7 lesson).
static __device__ __forceinline__ void axstore(float* p, float v)
{
    __hip_atomic_exchange((unsigned int*)p, __builtin_bit_cast(unsigned int, v),
                          __ATOMIC_RELAXED, __HIP_MEMORY_SCOPE_AGENT);
}
static __device__ __forceinline__ float axload(float* p)
{
    unsigned int u = __hip_atomic_fetch_add((unsigned int*)p, 0u,
                          __ATOMIC_RELAXED, __HIP_MEMORY_SCOPE_AGENT);
    return __builtin_bit_cast(float, u);
}
static __device__ __forceinline__ void setflag(unsigned int* f)
{
    // callers place this AFTER __syncthreads() (which drains every wave's vmcnt,
    // so all exchange-atomics have reached the coherence point before the flag).
    if (threadIdx.x == 0)
        __hip_atomic_fetch_add(f, 1u, __ATOMIC_RELAXED, __HIP_MEMORY_SCOPE_AGENT);
}
static __device__ __forceinline__ void waitflag(unsigned int* f)
{
    if (threadIdx.x == 0) {
        int sp = 0;
        while (__hip_atomic_fetch_add(f, 0u, __ATOMIC_RELAXED, __HIP_MEMORY_SCOPE_AGENT) == 0u) {
            __builtin_amdgcn_s_sleep(1);
            if (++sp > (1 << 25)) break;   // hang guard (never expected)
        }
    }
    __syncthreads();
}

// Per-wave GEMM, software-pipelined distance-1 register double-buffer on the
// global-streamed B operand (named buffers -> static indexing, no scratch).
// A (16 x Kd) from LDS [row][k]; B from global W^T [n][Kb] hi/lo planes.
// 3-MFMA split: ah*bh + ah*bl + al*bh, f32 accum.
template<int G>
static __device__ __forceinline__ void wgemm(
    const unsigned short* __restrict__ Ah, const unsigned short* __restrict__ Al, int lda, int Kd,
    const unsigned short* __restrict__ Bh, const unsigned short* __restrict__ Bl, int Kb,
    int nBase, int lane, f32x4 (&acc)[G])
{
    const int r16 = lane & 15, kg = lane >> 4;
    const unsigned short* ah = Ah + r16*lda + kg*8;
    const unsigned short* al = Al + r16*lda + kg*8;
    const unsigned short* bh0 = Bh + (size_t)(nBase + r16)*Kb + kg*8;
    const unsigned short* bl0 = Bl + (size_t)(nBase + r16)*Kb + kg*8;

    bf16x8 cbh[G], cbl[G], pbh[G], pbl[G];
#pragma unroll
    for (int j = 0; j < G; ++j) {
        cbh[j] = frag_ld(bh0 + (size_t)j*16*Kb);
        cbl[j] = frag_ld(bl0 + (size_t)j*16*Kb);
    }
    for (int k = 0; k < Kd; k += 64) {
#pragma unroll
        for (int j = 0; j < G; ++j) {
            pbh[j] = frag_ld(bh0 + (size_t)j*16*Kb + k + 32);
            pbl[j] = frag_ld(bl0 + (size_t)j*16*Kb + k + 32);
        }
        {
            bf16x8 a_h = frag_ld(ah + k), a_l = frag_ld(al + k);
#pragma unroll
            for (int j = 0; j < G; ++j) {
                acc[j] = __builtin_amdgcn_mfma_f32_16x16x32_bf16(a_h, cbh[j], acc[j], 0, 0, 0);
                acc[j] = __builtin_amdgcn_mfma_f32_16x16x32_bf16(a_h, cbl[j], acc[j], 0, 0, 0);
                acc[j] = __builtin_amdgcn_mfma_f32_16x16x32_bf16(a_l, cbh[j], acc[j], 0, 0, 0);
            }
        }
        if (k + 64 < Kd) {
#pragma unroll
            for (int j = 0; j < G; ++j) {
                cbh[j] = frag_ld(bh0 + (size_t)j*16*Kb + k + 64);
                cbl[j] = frag_ld(bl0 + (size_t)j*16*Kb + k + 64);
            }
        }
        {
            bf16x8 a_h = frag_ld(ah + k + 32), a_l = frag_ld(al + k + 32);
#pragma unroll
            for (int j = 0; j < G; ++j) {
                acc[j] = __builtin_amdgcn_mfma_f32_16x16x32_bf16(a_h, pbh[j], acc[j], 0, 0, 0);
                acc[j] = __builtin_amdgcn_mfma_f32_16x16x32_bf16(a_h, pbl[j], acc[j], 0, 0, 0);
                acc[j] = __builtin_amdgcn_mfma_f32_16x16x32_bf16(a_l, pbh[j], acc[j], 0, 0, 0);
            }
        }
    }
}

// Persistent pair-split kernel: 256 blocks = 128 row-slabs x 2 col-groups.
// Block (slab, cg) owns 16 rows end-to-end; cg0/cg1 split the gw2 N-dim (P2g/P4)
// and exchange tiny per-pair slices (yt/dr/y1 halves) via coherence-point atomics.
// C/D frag: col = lane&15, row = (lane>>4)*4 + reg.
__global__ __launch_bounds__(THREADS, 2) void sde_k(
    const float* __restrict__ ts, const float* __restrict__ dW,
    const float* __restrict__ g_w1, const float* __restrict__ g_b1,
    const float* __restrict__ f_w1, const float* __restrict__ f_b1,
    const float* __restrict__ f_b2, const float* __restrict__ f_b3,
    const float* __restrict__ g_b2,
    const unsigned short* __restrict__ w1tH, const unsigned short* __restrict__ w1tL,
    const unsigned short* __restrict__ gw2H, const unsigned short* __restrict__ gw2L,
    const unsigned short* __restrict__ fw2H, const unsigned short* __restrict__ fw2L,
    const unsigned short* __restrict__ fw3H, const unsigned short* __restrict__ fw3L,
    float* out, unsigned int* flags, float* xbuf)
{
    __shared__ __align__(16) unsigned short HAh[R_*AST], HAl[R_*AST]; // cols 0-511 g / 512-1023 f (HB aliases f-half)
    __shared__ __align__(16) unsigned short ycH[R_*YST], ycL[R_*YST]; // yc, aliased as yt after P1
    __shared__ float y_s[R_*FP_], gp_s[R_*FP_], dr_s[R_*FP_];

    const int bid = blockIdx.x, tid = threadIdx.x;
    const int cg = bid & 1, slab = bid >> 1, r0 = slab * R_;
    const int w = tid >> 6, lane = tid & 63, r16 = lane & 15, kg = lane >> 4;
    const int pcg = cg ^ 1;

    unsigned int* fl = flags + (size_t)slab * (NSTEP * 8);
    float* xE1 = xbuf + (size_t)slab * 3072;   // [2][16][64] yt halves
    float* xE2 = xE1 + 2048;                   // [16][64]    dr upper half

    // prologue: y0 (encoder output; kernel boundary = coherent)
    for (int i = tid; i < R_*128; i += THREADS) {
        int row = i >> 7, col = i & 127;
        float v = out[(size_t)(r0 + row)*S_ + col];
        y_s[row*FP_ + col] = v;
        unsigned short h, lo; f2b2(v, h, lo);
        ycH[row*YST + col] = h; ycL[row*YST + col] = lo;
    }
    __syncthreads();

    for (int step = 0; step < NSTEP; ++step) {
        const float tcur = ts[3+step];
        const float dt   = ts[4+step] - tcur;
        const float sq   = sqrtf(dt);
        const float* dWs = dW + (size_t)step * B_ * 16;
        unsigned int* f = fl + step*8;
        float* y1g = out + (size_t)(step+1) * B_ * S_;
        float dwv[4];
#pragma unroll
        for (int reg = 0; reg < 4; ++reg)
            dwv[reg] = dWs[(r0 + kg*4 + reg)*16 + r16] * sq;

        // ---- P1: HA-g (both groups); HA-f (cg0 only)
        {
            f32x4 acc[4] = {};
            wgemm<4>(ycH, ycL, YST, 128, w1tH, w1tL, 128, w*64, lane, acc);
#pragma unroll
            for (int j = 0; j < 4; ++j) {
                int col = w*64 + j*16 + r16;
                float be = g_b1[col] + tcur*g_w1[col];
#pragma unroll
                for (int reg = 0; reg < 4; ++reg) {
                    int row = kg*4 + reg;
                    float v = fmaxf(acc[j][reg] + be, 0.f);
                    unsigned short h, lo; f2b2(v, h, lo);
                    HAh[row*AST + col] = h; HAl[row*AST + col] = lo;
                }
            }
        }
        if (cg == 0) {
            f32x4 acc[4] = {};
            wgemm<4>(ycH, ycL, YST, 128, w1tH, w1tL, 128, 512 + w*64, lane, acc);
#pragma unroll
            for (int j = 0; j < 4; ++j) {
                int colg = 512 + w*64 + j*16 + r16;
                float be = f_b1[colg - 512] + tcur*f_w1[colg - 512];
#pragma unroll
                for (int reg = 0; reg < 4; ++reg) {
                    int row = kg*4 + reg;
                    float v = fmaxf(acc[j][reg] + be, 0.f);
                    unsigned short h, lo; f2b2(v, h, lo);
                    HAh[row*AST + colg] = h; HAl[row*AST + colg] = lo;
                }
            }
        }
        __syncthreads();

        // ---- P2g (own gw2 half): gp + yt own s-half; exchange yt half
        for (int grp = 0; grp < 2; ++grp) {
            f32x4 acc[4] = {};
            int nb = cg*1024 + w*128 + grp*64;
            wgemm<4>(HAh, HAl, AST, 512, gw2H, gw2L, 512, nb, lane, acc);
#pragma unroll
            for (int j = 0; j < 4; ++j) {
                float bb = g_b2[nb + j*16 + r16];
#pragma unroll
                for (int reg = 0; reg < 4; ++reg) {
                    float m = (acc[j][reg] + bb) * dwv[reg];
                    m += __shfl_xor(m,1); m += __shfl_xor(m,2);
                    m += __shfl_xor(m,4); m += __shfl_xor(m,8);
                    if (r16 == 0) {
                        int row = kg*4 + reg;
                        int s = (nb >> 4) + j;
                        int idx = row*FP_ + s;
                        gp_s[idx] = m;
                        float yv = y_s[idx] + m;
                        unsigned short h, lo; f2b2(yv, h, lo);
                        ycH[row*YST + s] = h; ycL[row*YST + s] = lo;
                        axstore(&xE1[cg*1024 + row*64 + (s - cg*64)], yv);
                    }
                }
            }
        }
        __syncthreads();           // drains vmcnt -> exchange atomics complete
        setflag(&f[cg]);

        // ---- P2f (cg0): HB = relu(HA_f @ f_w2 + b), stored over HA-f
        if (cg == 0) {
            f32x4 acc[4] = {};
            wgemm<4>(HAh + 512, HAl + 512, AST, 512, fw2H, fw2L, 512, w*64, lane, acc);
            __syncthreads();       // everyone done READING HA-f before overwrite
#pragma unroll
            for (int j = 0; j < 4; ++j) {
                int col = w*64 + j*16 + r16;
                float be = f_b2[col];
#pragma unroll
                for (int reg = 0; reg < 4; ++reg) {
                    int row = kg*4 + reg;
                    float v = fmaxf(acc[j][reg] + be, 0.f);
                    unsigned short h, lo; f2b2(v, h, lo);
                    (HAh + 512)[row*AST + col] = h; (HAl + 512)[row*AST + col] = lo;
                }
            }
        }

        // ---- E1 consume: partner's yt half
        waitflag(&f[pcg]);
        for (int i = tid; i < 1024; i += THREADS) {
            int row = i >> 6, s = pcg*64 + (i & 63);
            float yv = axload(&xE1[pcg*1024 + i]);
            unsigned short h, lo; f2b2(yv, h, lo);
            ycH[row*YST + s] = h; ycL[row*YST + s] = lo;
        }
        __syncthreads();

        // ---- P3a (both, redundant): HA2 = relu([t,yt]@g_w1+b) over HA-g
        {
            f32x4 acc[4] = {};
            wgemm<4>(ycH, ycL, YST, 128, w1tH, w1tL, 128, w*64, lane, acc);
#pragma unroll
            for (int j = 0; j < 4; ++j) {
                int col = w*64 + j*16 + r16;
                float be = g_b1[col] + tcur*g_w1[col];
#pragma unroll
                for (int reg = 0; reg < 4; ++reg) {
                    int row = kg*4 + reg;
                    float v = fmaxf(acc[j][reg] + be, 0.f);
                    unsigned short h, lo; f2b2(v, h, lo);
                    HAh[row*AST + col] = h; HAl[row*AST + col] = lo;
                }
            }
        }

        // ---- P3b (cg0): drift; exchange upper half.  cg1: receive.
        if (cg == 0) {
            f32x4 acc1[1] = {};
            wgemm<1>(HAh + 512, HAl + 512, AST, 512, fw3H, fw3L, 512, w*16, lane, acc1);
            int col = w*16 + r16;
            float be = f_b3[col];
#pragma unroll
            for (int reg = 0; reg < 4; ++reg) {
                int row = kg*4 + reg;
                float dv = acc1[0][reg] + be;
                dr_s[row*FP_ + col] = dv;
                if (col >= 64) axstore(&xE2[row*64 + (col - 64)], dv);
            }
            __syncthreads();       // HA2 + dr_s + exchange drained
            setflag(&f[2]);
        } else {
            __syncthreads();       // own P3a HA2 writes visible
            waitflag(&f[2]);
            for (int i = tid; i < 1024; i += THREADS) {
                int row = i >> 6, c = 64 + (i & 63);
                dr_s[row*FP_ + c] = axload(&xE2[i]);
            }
            __syncthreads();
        }

        // ---- P4 (own gw2 half): gp2 + final update for own s-half
        for (int grp = 0; grp < 2; ++grp) {
            f32x4 acc[4] = {};
            int nb = cg*1024 + w*128 + grp*64;
            wgemm<4>(HAh, HAl, AST, 512, gw2H, gw2L, 512, nb, lane, acc);
#pragma unroll
            for (int j = 0; j < 4; ++j) {
                float bb = g_b2[nb + j*16 + r16];
#pragma unroll
                for (int reg = 0; reg < 4; ++reg) {
                    float m = (acc[j][reg] + bb) * dwv[reg];
                    m += __shfl_xor(m,1); m += __shfl_xor(m,2);
                    m += __shfl_xor(m,4); m += __shfl_xor(m,8);
                    if (r16 == 0) {
                        int row = kg*4 + reg;
                        int s = (nb >> 4) + j;
                        int idx = row*FP_ + s;
                        float v1 = y_s[idx] + dr_s[idx]*dt + 0.5f*(gp_s[idx] + m);
                        axstore(&y1g[(size_t)(r0 + row)*S_ + s], v1);
                        y_s[idx] = v1;
                        unsigned short h, lo; f2b2(v1, h, lo);
                        ycH[row*YST + s] = h; ycL[row*YST + s] = lo;
                    }
                }
            }
        }
        __syncthreads();
        setflag(&f[3 + cg]);
        waitflag(&f[3 + pcg]);
        for (int i = tid; i < 1024; i += THREADS) {
            int row = i >> 6, s = pcg*64 + (i & 63);
            float v = axload(&y1g[(size_t)(r0 + row)*S_ + s]);
            unsigned short h, lo; f2b2(v, h, lo);
            ycH[row*YST + s] = h; ycL[row*YST + s] = lo;
        }
        __syncthreads();
    }
}

// transpose + split-cast: in (rows=[rowOff..rowOff+Kd) x N f32) -> out [N][Kd] hi/lo
__global__ __launch_bounds__(256) void tcast_k(
    const float* __restrict__ in, int rowOff, int Kd, int N,
    unsigned short* __restrict__ outH, unsigned short* __restrict__ outL)
{
    __shared__ float tl[32][33];
    const int kb = blockIdx.x*32, nb = blockIdx.y*32;
    const int tx = threadIdx.x, ty = threadIdx.y;
    for (int r = ty; r < 32; r += 8)
        tl[r][tx] = in[(size_t)(rowOff + kb + r)*N + nb + tx];
    __syncthreads();
    for (int r = ty; r < 32; r += 8) {
        unsigned short h, lo; f2b2(tl[tx][r], h, lo);
        size_t o = (size_t)(nb + r)*Kd + kb + tx;
        outH[o] = h; outL[o] = lo;
    }
}

__global__ __launch_bounds__(128) void encoder_k(
    const float* __restrict__ x,
    const float* __restrict__ w1, const float* __restrict__ b1,
    const float* __restrict__ w2, const float* __restrict__ b2,
    float* __restrict__ y0)
{
    int b = blockIdx.x;
    __shared__ float h[H_];
    int tid = threadIdx.x;
    float x0 = x[b*3+0], x1 = x[b*3+1], x2 = x[b*3+2];
    for (int i = tid; i < H_; i += 128)
        h[i] = fmaxf(x0*w1[i] + x1*w1[H_+i] + x2*w1[2*H_+i] + b1[i], 0.f);
    __syncthreads();
    float acc = b2[tid];
    for (int k = 0; k < H_; ++k) acc += h[k]*w2[k*S_+tid];
    y0[(size_t)b*S_ + tid] = acc;
}

extern "C" void kernel_launch(void* const* d_in, const int* in_sizes, int n_in,
                              void* d_out, int out_size, void* d_ws, size_t ws_size,
                              hipStream_t stream)
{
    const float* ts     = (const float*)d_in[0];
    const float* x      = (const float*)d_in[1];
    const float* enc_w1 = (const float*)d_in[2];
    const float* enc_b1 = (const float*)d_in[3];
    const float* enc_w2 = (const float*)d_in[4];
    const float* enc_b2 = (const float*)d_in[5];
    const float* f_w1   = (const float*)d_in[6];
    const float* f_b1   = (const float*)d_in[7];
    const float* f_w2   = (const float*)d_in[8];
    const float* f_b2   = (const float*)d_in[9];
    const float* f_w3   = (const float*)d_in[10];
    const float* f_b3   = (const float*)d_in[11];
    const float* g_w1   = (const float*)d_in[12];
    const float* g_b1   = (const float*)d_in[13];
    const float* g_w2   = (const float*)d_in[14];
    const float* g_b2   = (const float*)d_in[15];
    const float* dW     = (const float*)d_in[16];

    float* out = (float*)d_out;
    unsigned short* wsp = (unsigned short*)d_ws;

    unsigned short* w1tH = wsp;                     // [1024][128]
    unsigned short* w1tL = w1tH + 1024*128;
    unsigned short* gw2H = w1tL + 1024*128;         // [2048][512]
    unsigned short* gw2L = gw2H + 2048*512;
    unsigned short* fw2H = gw2L + 2048*512;         // [512][512]
    unsigned short* fw2L = fw2H + 512*512;
    unsigned short* fw3H = fw2L + 512*512;          // [128][512]
    unsigned short* fw3L = fw3H + 128*512;
    unsigned int*   flags = (unsigned int*)(fw3L + 128*512);   // 128*512 uints
    float*          xbuf  = (float*)(flags + 128*512);         // 128*3072 floats

    dim3 tb(32,8);
    tcast_k<<<dim3(4,16),  tb, 0, stream>>>(g_w1, 1, 128, 512,  w1tH,         w1tL);
    tcast_k<<<dim3(4,16),  tb, 0, stream>>>(f_w1, 1, 128, 512,  w1tH+512*128, w1tL+512*128);
    tcast_k<<<dim3(16,16), tb, 0, stream>>>(f_w2, 0, 512, 512,  fw2H,         fw2L);
    tcast_k<<<dim3(16,4),  tb, 0, stream>>>(f_w3, 0, 512, 128,  fw3H,         fw3L);
    tcast_k<<<dim3(16,64), tb, 0, stream>>>(g_w2, 0, 512, 2048, gw2H,         gw2L);

    encoder_k<<<B_, 128, 0, stream>>>(x, enc_w1, enc_b1, enc_w2, enc_b2, out);
    hipMemsetAsync(flags, 0, 128*512*sizeof(unsigned int), stream);

    sde_k<<<NBLK, THREADS, 0, stream>>>(
        ts, dW, g_w1, g_b1, f_w1, f_b1, f_b2, f_b3, g_b2,
        w1tH, w1tL, gw2H, gw2L, fw2H, fw2L, fw3H, fw3L,
        out, flags, xbuf);
}